// Round 2
// baseline (138.087 us; speedup 1.0000x reference)
//
#include <hip/hip_runtime.h>

// firing_model: the reference scan starts from the zero vector, and
// nxt = -prev + tanh(prev @ x) fixes zero (tanh(0)=0) — the 500k-step
// recurrence is dead code and the output is exactly zeros.
//
// Round-1 evidence: the harness's own rocclr fillBufferAligned hits 6.6 TB/s
// on this device, while my hand-rolled float4 zero-fill ran at ~2.7 TB/s.
// So delegate to the vendor fill via hipMemsetAsync (graph-capturable; the
// harness captures the same op class for its poison resets).

extern "C" void kernel_launch(void* const* d_in, const int* in_sizes, int n_in,
                              void* d_out, int out_size, void* d_ws, size_t ws_size,
                              hipStream_t stream) {
    (void)d_in; (void)in_sizes; (void)n_in; (void)d_ws; (void)ws_size;

    // 34,486,200 floats = 137.9 MB of exact zeros. IEEE-754 zero is all-zero
    // bytes, so a byte-wise memset of 0 is the correct float fill.
    size_t bytes = (size_t)out_size * sizeof(float);
    hipMemsetAsync(d_out, 0, bytes, stream);
}